// Round 4
// baseline (456.867 us; speedup 1.0000x reference)
//
#include <hip/hip_runtime.h>
#include <math.h>

// Problem constants: B=1024, T=256, D=128, H=64, 4H=256
constexpr int B_ = 1024;
constexpr int T_ = 256;
constexpr int D_ = 128;
constexpr int H_ = 64;
constexpr int G_ = 256;
constexpr int M_ = B_ * T_;

typedef short     v8s __attribute__((ext_vector_type(8)));   // 8 bf16
typedef float     v4f __attribute__((ext_vector_type(4)));   // MFMA acc
typedef _Float16  h2  __attribute__((ext_vector_type(2)));   // packed f16

__device__ __forceinline__ float sigmoidf_(float x) {
    return 1.0f / (1.0f + __expf(-x));
}
// tanh(x) = 2*sigmoid(2x) - 1 ; overflow-safe at both ends
__device__ __forceinline__ float tanhf_(float x) {
    return fmaf(2.0f, 1.0f / (1.0f + __expf(-2.0f * x)), -1.0f);
}
__device__ __forceinline__ unsigned short f2bf(float f) {   // RNE f32->bf16
    unsigned u = __float_as_uint(f);
    u = (u + 0x7fffu + ((u >> 16) & 1u)) >> 16;
    return (unsigned short)u;
}
__device__ __forceinline__ v8s pack8(float4 a, float4 b) {
    v8s r;
    r[0] = (short)f2bf(a.x); r[1] = (short)f2bf(a.y);
    r[2] = (short)f2bf(a.z); r[3] = (short)f2bf(a.w);
    r[4] = (short)f2bf(b.x); r[5] = (short)f2bf(b.y);
    r[6] = (short)f2bf(b.z); r[7] = (short)f2bf(b.w);
    return r;
}
__device__ __forceinline__ unsigned pkh2(float a, float b) {  // 2xf32 -> packed f16
    h2 v; v[0] = (_Float16)a; v[1] = (_Float16)b;
    return __builtin_bit_cast(unsigned, v);
}
// f16x2 dot with f32 accumulate (v_dot2_f32_f16); safe fallback if missing
__device__ __forceinline__ float fdot2_(unsigned a, unsigned b, float c) {
#if __has_builtin(__builtin_amdgcn_fdot2)
    return __builtin_amdgcn_fdot2(__builtin_bit_cast(h2, a),
                                  __builtin_bit_cast(h2, b), c, false);
#else
    h2 ha = __builtin_bit_cast(h2, a), hb = __builtin_bit_cast(h2, b);
    return c + (float)ha[0] * (float)hb[0] + (float)ha[1] * (float)hb[1];
#endif
}

// ---------------------------------------------------------------------------
// Phase 1: xp[b][t][g] (f16, bias folded) = W_ih @ x^T. 1024 blocks
// (16 t x 64 batch-blocks), 256 thr. Unchanged from R1 (its counters surface
// next round once rec drops below it).
// ---------------------------------------------------------------------------
__global__ __launch_bounds__(256, 2)
void xproj_f16_kernel(const float* __restrict__ x,       // [B,T,D]
                      const float* __restrict__ W_ih,    // [256,128]
                      const float* __restrict__ b_ih,    // [256]
                      const float* __restrict__ b_hh,    // [256]
                      unsigned short* __restrict__ xp)   // [B][T][256] f16
{
    const int tch  = blockIdx.x;     // 0..15 : t = tch*16 + tl
    const int bblk = blockIdx.y;     // 0..63 : batches bblk*16..+15
    const int tid  = threadIdx.x;
    const int wv   = tid >> 6;
    const int lane = tid & 63;
    const int q    = lane >> 4;
    const int ml   = lane & 15;

    __shared__ __align__(16) unsigned short xs[16][136];   // x tile bf16, pad+8
    __shared__ __align__(16) unsigned short tbuf[16][272]; // [batch][gate] f16

    // ---- wave-resident A-frags + bias: gate tiles gt = cls*4 + wv ----
    v8s afr[4][4];   // [cls][ks]
    v4f bias[4];
    #pragma unroll
    for (int cls = 0; cls < 4; ++cls) {
        const int gr = (cls * 4 + wv) * 16 + ml;       // A m-index = ml
        #pragma unroll
        for (int ks = 0; ks < 4; ++ks) {
            const float* p = W_ih + (size_t)gr * D_ + ks * 32 + q * 8;
            afr[cls][ks] = pack8(((const float4*)p)[0], ((const float4*)p)[1]);
        }
        #pragma unroll
        for (int r = 0; r < 4; ++r) {
            const int g2 = (cls * 4 + wv) * 16 + q * 4 + r;   // C row = q*4+r
            bias[cls][r] = b_ih[g2] + b_hh[g2];
        }
    }

    for (int tl = 0; tl < 16; ++tl) {
        const int t = tch * 16 + tl;

        // ---- stage x tile: 16 batches x 128 f32 -> bf16 LDS ----
        #pragma unroll
        for (int i = 0; i < 2; ++i) {
            int f4  = tid + i * 256;          // 512 float4s
            int row = f4 >> 5, c4 = f4 & 31;
            float4 v = ((const float4*)(x + ((size_t)(bblk * 16 + row) * T_
                                             + t) * D_))[c4];
            short4 s;
            s.x = (short)f2bf(v.x); s.y = (short)f2bf(v.y);
            s.z = (short)f2bf(v.z); s.w = (short)f2bf(v.w);
            *(short4*)&xs[row][c4 * 4] = s;
        }
        __syncthreads();   // bar1: xs ready (also protects prev tbuf readers)

        // ---- MFMA: 4 C-tiles per wave, K=128 ----
        v4f acc[4];
        #pragma unroll
        for (int cls = 0; cls < 4; ++cls) acc[cls] = bias[cls];
        #pragma unroll
        for (int ks = 0; ks < 4; ++ks) {
            v8s bf = *(const v8s*)&xs[ml][ks * 32 + q * 8];   // B: n=ml, k
            #pragma unroll
            for (int cls = 0; cls < 4; ++cls)
                acc[cls] = __builtin_amdgcn_mfma_f32_16x16x32_bf16(
                    afr[cls][ks], bf, acc[cls], 0, 0, 0);
        }

        // ---- pack f16 -> tbuf[batch=ml][gate] ----
        #pragma unroll
        for (int cls = 0; cls < 4; ++cls) {
            uint2 pk;
            pk.x = pkh2(acc[cls][0], acc[cls][1]);
            pk.y = pkh2(acc[cls][2], acc[cls][3]);
            *(uint2*)&tbuf[ml][cls * 64 + wv * 16 + q * 4] = pk;
        }
        __syncthreads();   // bar2: tbuf ready; all xs reads done

        // ---- coalesced store: thread covers 16 gates of one (b,t) row ----
        {
            const int br = tid >> 4, seg = tid & 15;
            uint4 r0 = *(const uint4*)&tbuf[br][seg * 16];
            uint4 r1 = *(const uint4*)&tbuf[br][seg * 16 + 8];
            unsigned short* orow = xp + ((size_t)(bblk * 16 + br) * T_ + t) * G_
                                      + seg * 16;
            *(uint4*)orow       = r0;
            *(uint4*)(orow + 8) = r1;
        }
    }
}

// ---------------------------------------------------------------------------
// Phase 2 (R2): gate-pair split recurrence. 1024 blocks x 128 thr (2 waves
// per batch -> 2048 waves = 2 waves/SIMD, co-resident blocks hide stalls).
// Row map: wave w, half sel=lane>>5, u = w*32+(lane&31):
//   sel=0 -> rows {u, 64+u}       (i,f for unit u)
//   sel=1 -> rows {128+u, 192+u}  (g,o for unit u)
// Matvec: 64 dot2/lane/step (was 128). Gates cross lanes via __shfl_xor(32)
// (intra-wave, no LDS). Only h (128 B) crosses waves: ds_write + lgkmcnt(0)
// + raw s_barrier -- NO vmcnt drain, so the depth-2 xp prefetch stays in
// flight across steps. Safety: each wave's ds_reads of hb[par] are consumed
// by the dot2s before it can reach the barrier, so the end-of-step barrier
// alone protects the next step's overwrite of hb[par].
// ---------------------------------------------------------------------------
__global__ __launch_bounds__(128, 2)
void rec_wave2_kernel(const unsigned short* __restrict__ xp,  // [B][T][256] f16
                      const float* __restrict__ W_hh,   // [256,64]
                      const float* __restrict__ W1,     // [32,64]
                      const float* __restrict__ b1,     // [32]
                      const float* __restrict__ W2,     // [1,32]
                      const float* __restrict__ b2,     // [1]
                      float* __restrict__ out)          // [B]
{
    const int b    = blockIdx.x;
    const int tid  = threadIdx.x;
    const int wv   = tid >> 6;           // wave 0/1
    const int lane = tid & 63;
    const int sel  = lane >> 5;          // 0: i,f rows ; 1: g,o rows
    const int u    = (wv << 5) | (lane & 31);   // hidden unit 0..63
    const int rowA = sel * 128 + u;      // i (sel=0) or g (sel=1)
    const int rowB = rowA + 64;          // f (sel=0) or o (sel=1)

    __shared__ __align__(16) unsigned hb[2][32];   // h as 64 f16, dbuf
    __shared__ float hf[H_];
    __shared__ float ys[32];

    // ---- pack W_hh rows rowA,rowB as f16 pairs: 8 uint4 each (64 VGPR) ----
    uint4 wA[8], wB[8];
    #pragma unroll
    for (int k8 = 0; k8 < 8; ++k8) {
        const float* pA = W_hh + (size_t)rowA * H_ + k8 * 8;
        float4 a0 = ((const float4*)pA)[0];
        float4 a1 = ((const float4*)pA)[1];
        wA[k8].x = pkh2(a0.x, a0.y); wA[k8].y = pkh2(a0.z, a0.w);
        wA[k8].z = pkh2(a1.x, a1.y); wA[k8].w = pkh2(a1.z, a1.w);
        const float* pB = W_hh + (size_t)rowB * H_ + k8 * 8;
        float4 b0 = ((const float4*)pB)[0];
        float4 b1v = ((const float4*)pB)[1];
        wB[k8].x = pkh2(b0.x, b0.y); wB[k8].y = pkh2(b0.z, b0.w);
        wB[k8].z = pkh2(b1v.x, b1v.y); wB[k8].w = pkh2(b1v.z, b1v.w);
    }

    if (tid < 32) hb[0][tid] = 0u;       // h(0) = 0
    float c = 0.0f, hval = 0.0f;

    const unsigned short* __restrict__ xbase = xp + (size_t)b * T_ * G_;
    // depth-2 prefetch: entering step t, xA0/xB0 = xp[t], xA1/xB1 = xp[t+1]
    unsigned short xA0 = xbase[rowA],      xB0 = xbase[rowB];
    unsigned short xA1 = xbase[G_ + rowA], xB1 = xbase[G_ + rowB];
    __syncthreads();   // hb zeros + W_hh packing done (also orders prefetch)

    for (int t = 0; t < T_; ++t) {
        const int par = t & 1;
        // ---- issue prefetch for t+2 (consumed 2 steps from now) ----
        const int tn = (t + 2 < T_) ? t + 2 : T_ - 1;
        const unsigned short* xnp = xbase + (size_t)tn * G_;
        unsigned short xA2 = xnp[rowA], xB2 = xnp[rowB];

        // ---- matvec: 2 rows x K=64 -> 64 dot2, 4 accumulation chains ----
        const uint4* hb4 = (const uint4*)hb[par];
        float aA0 = 0.f, aA1 = 0.f, aB0 = 0.f, aB1 = 0.f;
        #pragma unroll
        for (int k8 = 0; k8 < 8; ++k8) {
            uint4 hv = hb4[k8];              // broadcast b128, conflict-free
            aA0 = fdot2_(wA[k8].x, hv.x, aA0);
            aA1 = fdot2_(wA[k8].y, hv.y, aA1);
            aA0 = fdot2_(wA[k8].z, hv.z, aA0);
            aA1 = fdot2_(wA[k8].w, hv.w, aA1);
            aB0 = fdot2_(wB[k8].x, hv.x, aB0);
            aB1 = fdot2_(wB[k8].y, hv.y, aB1);
            aB0 = fdot2_(wB[k8].z, hv.z, aB0);
            aB1 = fdot2_(wB[k8].w, hv.w, aB1);
        }
        float preA = (float)__builtin_bit_cast(_Float16, xA0) + (aA0 + aA1);
        float preB = (float)__builtin_bit_cast(_Float16, xB0) + (aB0 + aB1);

        // ---- activations (branchless): A = sigmoid | tanh, B = sigmoid ----
        // tanh(x) = 2*sigmoid(2x)-1 -> scale/offset form keeps code uniform
        const float scale = sel ? 2.0f : 1.0f;
        const float off   = sel ? -1.0f : 0.0f;
        float gA = fmaf(scale, sigmoidf_(scale * preA), off);  // i or g
        float gB = sigmoidf_(preB);                            // f or o

        // ---- bring (g,o) to the i,f half (intra-wave, f32 exact) ----
        float gsw = __shfl_xor(gA, 32, 64);
        float osw = __shfl_xor(gB, 32, 64);

        if (sel == 0) {     // cell update for unit u, lanes 0..31 of each wave
            float gi = gA, gf = gB, gg = gsw, go = osw;
            c    = fmaf(gf, c, gi * gg);
            hval = go * tanhf_(c);
            ((_Float16*)hb[par ^ 1])[u] = (_Float16)hval;
        }
        // h write visible to both waves; NO vmcnt drain (prefetch in flight)
        asm volatile("s_waitcnt lgkmcnt(0)" ::: "memory");
        __builtin_amdgcn_s_barrier();
        asm volatile("" ::: "memory");

        xA0 = xA1; xB0 = xB1; xA1 = xA2; xB1 = xB2;
    }

    // ---- head (once) ----
    if (sel == 0) hf[u] = hval;
    __syncthreads();
    if (tid < 32) {
        float acc = b1[tid];
        const float4* w1r = (const float4*)(W1 + (size_t)tid * H_);
        #pragma unroll
        for (int k4 = 0; k4 < 16; ++k4) {
            float4 h4 = *(const float4*)&hf[k4 * 4];
            float4 w4 = w1r[k4];
            acc = fmaf(w4.x, h4.x, acc); acc = fmaf(w4.y, h4.y, acc);
            acc = fmaf(w4.z, h4.z, acc); acc = fmaf(w4.w, h4.w, acc);
        }
        ys[tid] = fmaxf(acc, 0.0f);
    }
    __syncthreads();
    if (tid == 0) {
        float acc = b2[0];
        #pragma unroll
        for (int j = 0; j < 32; ++j) acc = fmaf(W2[j], ys[j], acc);
        out[b] = sigmoidf_(acc);
    }
}

// ---------------------------------------------------------------------------
// Fallback: round-1 fused fp32 kernel (used only if workspace too small).
// ---------------------------------------------------------------------------
__global__ __launch_bounds__(256, 2)
void lstm_fused_kernel(const float* __restrict__ x,
                       const float* __restrict__ W_ih,
                       const float* __restrict__ W_hh,
                       const float* __restrict__ b_ih,
                       const float* __restrict__ b_hh,
                       const float* __restrict__ W1,
                       const float* __restrict__ b1,
                       const float* __restrict__ W2,
                       const float* __restrict__ b2,
                       float* __restrict__ out)
{
    const int b = blockIdx.x;
    const int g = threadIdx.x;

    __shared__ __align__(16) float xs[D_];
    __shared__ __align__(16) float hs[H_];
    __shared__ __align__(16) float gts[G_];
    __shared__ __align__(16) float yss[32];

    float wih[D_];
    float whhr[H_];
    {
        const float4* wr = (const float4*)(W_ih + (size_t)g * D_);
        #pragma unroll
        for (int k = 0; k < D_ / 4; ++k) {
            float4 v = wr[k];
            wih[4*k+0] = v.x; wih[4*k+1] = v.y;
            wih[4*k+2] = v.z; wih[4*k+3] = v.w;
        }
    }
    {
        const float4* wr = (const float4*)(W_hh + (size_t)g * H_);
        #pragma unroll
        for (int k = 0; k < H_ / 4; ++k) {
            float4 v = wr[k];
            whhr[4*k+0] = v.x; whhr[4*k+1] = v.y;
            whhr[4*k+2] = v.z; whhr[4*k+3] = v.w;
        }
    }
    const float bg  = b_ih[g] + b_hh[g];
    const int   cls = g >> 6;

    float c = 0.0f;
    if (g < H_) hs[g] = 0.0f;

    const float* __restrict__ xrow = x + (size_t)b * T_ * D_;

    for (int t = 0; t < T_; ++t) {
        if (g < D_) xs[g] = xrow[(size_t)t * D_ + g];
        __syncthreads();

        float a0 = bg, a1 = 0.f, a2 = 0.f, a3 = 0.f;
        const float4* xs4 = (const float4*)xs;
        #pragma unroll
        for (int k = 0; k < D_ / 4; ++k) {
            float4 v = xs4[k];
            a0 = fmaf(wih[4*k+0], v.x, a0);
            a1 = fmaf(wih[4*k+1], v.y, a1);
            a2 = fmaf(wih[4*k+2], v.z, a2);
            a3 = fmaf(wih[4*k+3], v.w, a3);
        }
        const float4* hs4 = (const float4*)hs;
        #pragma unroll
        for (int k = 0; k < H_ / 4; ++k) {
            float4 v = hs4[k];
            a0 = fmaf(whhr[4*k+0], v.x, a0);
            a1 = fmaf(whhr[4*k+1], v.y, a1);
            a2 = fmaf(whhr[4*k+2], v.z, a2);
            a3 = fmaf(whhr[4*k+3], v.w, a3);
        }
        float acc = (a0 + a1) + (a2 + a3);
        gts[g] = (cls == 2) ? tanhf_(acc) : sigmoidf_(acc);
        __syncthreads();

        if (g < H_) {
            float gi = gts[g];
            float gf = gts[H_ + g];
            float gg = gts[2 * H_ + g];
            float go = gts[3 * H_ + g];
            c = fmaf(gf, c, gi * gg);
            hs[g] = go * tanhf_(c);
        }
    }
    __syncthreads();

    if (g < 32) {
        float acc = b1[g];
        const float* w1r = W1 + g * H_;
        #pragma unroll
        for (int k = 0; k < H_; ++k) acc = fmaf(w1r[k], hs[k], acc);
        yss[g] = fmaxf(acc, 0.0f);
    }
    __syncthreads();
    if (g == 0) {
        float acc = b2[0];
        #pragma unroll
        for (int k = 0; k < 32; ++k) acc = fmaf(W2[k], yss[k], acc);
        out[b] = sigmoidf_(acc);
    }
}

extern "C" void kernel_launch(void* const* d_in, const int* in_sizes, int n_in,
                              void* d_out, int out_size, void* d_ws, size_t ws_size,
                              hipStream_t stream) {
    const float* x    = (const float*)d_in[0];
    const float* W_ih = (const float*)d_in[1];
    const float* W_hh = (const float*)d_in[2];
    const float* b_ih = (const float*)d_in[3];
    const float* b_hh = (const float*)d_in[4];
    const float* W1   = (const float*)d_in[5];
    const float* b1   = (const float*)d_in[6];
    const float* W2   = (const float*)d_in[7];
    const float* b2   = (const float*)d_in[8];
    float* out = (float*)d_out;

    const size_t xp_bytes = (size_t)M_ * G_ * sizeof(unsigned short);  // 134 MB

    if (ws_size >= xp_bytes) {
        unsigned short* xp = (unsigned short*)d_ws;
        xproj_f16_kernel<<<dim3(16, 64), dim3(256), 0, stream>>>(
            x, W_ih, b_ih, b_hh, xp);
        rec_wave2_kernel<<<dim3(B_), dim3(128), 0, stream>>>(
            xp, W_hh, W1, b1, W2, b2, out);
    } else {
        lstm_fused_kernel<<<dim3(B_), dim3(256), 0, stream>>>(
            x, W_ih, W_hh, b_ih, b_hh, W1, b1, W2, b2, out);
    }
}

// Round 5
// 423.678 us; speedup vs baseline: 1.0783x; 1.0783x over previous
//
#include <hip/hip_runtime.h>
#include <math.h>

// Problem constants: B=1024, T=256, D=128, H=64, 4H=256
constexpr int B_ = 1024;
constexpr int T_ = 256;
constexpr int D_ = 128;
constexpr int H_ = 64;
constexpr int G_ = 256;
constexpr int M_ = B_ * T_;

typedef short     v8s __attribute__((ext_vector_type(8)));   // 8 bf16
typedef float     v4f __attribute__((ext_vector_type(4)));   // MFMA acc
typedef _Float16  h2  __attribute__((ext_vector_type(2)));   // packed f16

__device__ __forceinline__ float sigmoidf_(float x) {
    return 1.0f / (1.0f + __expf(-x));
}
// tanh(x) = 2*sigmoid(2x) - 1 ; overflow-safe at both ends
__device__ __forceinline__ float tanhf_(float x) {
    return fmaf(2.0f, 1.0f / (1.0f + __expf(-2.0f * x)), -1.0f);
}
__device__ __forceinline__ unsigned short f2bf(float f) {   // RNE f32->bf16
    unsigned u = __float_as_uint(f);
    u = (u + 0x7fffu + ((u >> 16) & 1u)) >> 16;
    return (unsigned short)u;
}
__device__ __forceinline__ v8s pack8(float4 a, float4 b) {
    v8s r;
    r[0] = (short)f2bf(a.x); r[1] = (short)f2bf(a.y);
    r[2] = (short)f2bf(a.z); r[3] = (short)f2bf(a.w);
    r[4] = (short)f2bf(b.x); r[5] = (short)f2bf(b.y);
    r[6] = (short)f2bf(b.z); r[7] = (short)f2bf(b.w);
    return r;
}
__device__ __forceinline__ unsigned pkh2(float a, float b) {  // 2xf32 -> packed f16
    h2 v; v[0] = (_Float16)a; v[1] = (_Float16)b;
    return __builtin_bit_cast(unsigned, v);
}
// f16x2 dot with f32 accumulate (v_dot2_f32_f16); safe fallback if missing
__device__ __forceinline__ float fdot2_(unsigned a, unsigned b, float c) {
#if __has_builtin(__builtin_amdgcn_fdot2)
    return __builtin_amdgcn_fdot2(__builtin_bit_cast(h2, a),
                                  __builtin_bit_cast(h2, b), c, false);
#else
    h2 ha = __builtin_bit_cast(h2, a), hb = __builtin_bit_cast(h2, b);
    return c + (float)ha[0] * (float)hb[0] + (float)ha[1] * (float)hb[1];
#endif
}

// ---------------------------------------------------------------------------
// Phase 1 (R5): xp[b][t][g] (f16, bias folded) = W_ih @ x^T.
// Re-tiled for contiguity: block = (t-half, batch); tile = 16 CONSECUTIVE t
// of one batch -> x tile (8 KB) and xp store (8 KB) fully contiguous.
// x is loaded straight into MFMA B-fragments from global (no LDS staging,
// 4 waves share the tile via L1), with register prefetch of the next tile.
// tbuf (C bounce for f16 gate-contiguous stores) is double-buffered so the
// loop has exactly ONE raw s_barrier + lgkmcnt(0) per iter -- no vmcnt
// drain, so prefetch loads stay in flight across the barrier.
// ---------------------------------------------------------------------------
__global__ __launch_bounds__(256, 3)
void xproj2_kernel(const float* __restrict__ x,       // [B,T,D]
                   const float* __restrict__ W_ih,    // [256,128]
                   const float* __restrict__ b_ih,    // [256]
                   const float* __restrict__ b_hh,    // [256]
                   unsigned short* __restrict__ xp)   // [B][T][256] f16
{
    const int half = blockIdx.x;     // 0..1  : t base = half*128
    const int b    = blockIdx.y;     // 0..1023
    const int tid  = threadIdx.x;
    const int wv   = tid >> 6;
    const int lane = tid & 63;
    const int q    = lane >> 4;
    const int ml   = lane & 15;      // = t offset within tile (B n-index)

    __shared__ __align__(16) unsigned short tbuf[2][16][272]; // [par][t16][gate]

    // ---- wave-resident A-frags (W_ih) + bias: gate tiles gt = cls*4+wv ----
    v8s afr[4][4];   // [cls][ks]
    v4f bias[4];
    #pragma unroll
    for (int cls = 0; cls < 4; ++cls) {
        const int gr = (cls * 4 + wv) * 16 + ml;       // A m-index = ml
        #pragma unroll
        for (int ks = 0; ks < 4; ++ks) {
            const float* p = W_ih + (size_t)gr * D_ + ks * 32 + q * 8;
            afr[cls][ks] = pack8(((const float4*)p)[0], ((const float4*)p)[1]);
        }
        #pragma unroll
        for (int r = 0; r < 4; ++r) {
            const int g2 = (cls * 4 + wv) * 16 + q * 4 + r;   // C row = q*4+r
            bias[cls][r] = b_ih[g2] + b_hh[g2];
        }
    }

    // x row this lane reads: t = half*128 + tl*16 + ml (row advances by 16
    // rows = 16*D_ floats per iteration)
    const float* xrow = x + ((size_t)b * T_ + half * 128 + ml) * D_;

    // ---- register prefetch of the first tile (8 x float4 per lane) ----
    float4 rA[4], rB[4];
    #pragma unroll
    for (int ks = 0; ks < 4; ++ks) {
        const float* p = xrow + ks * 32 + q * 8;
        rA[ks] = ((const float4*)p)[0];
        rB[ks] = ((const float4*)p)[1];
    }

    for (int tl = 0; tl < 8; ++tl) {
        const int par = tl & 1;

        // ---- convert prefetched f32 -> bf16 B-frags ----
        v8s bf[4];
        #pragma unroll
        for (int ks = 0; ks < 4; ++ks) bf[ks] = pack8(rA[ks], rB[ks]);

        // ---- issue next tile's loads (drain at next iter's pack8) ----
        if (tl < 7) {
            const float* p2 = xrow + (size_t)(tl + 1) * 16 * D_;
            #pragma unroll
            for (int ks = 0; ks < 4; ++ks) {
                const float* p = p2 + ks * 32 + q * 8;
                rA[ks] = ((const float4*)p)[0];
                rB[ks] = ((const float4*)p)[1];
            }
        }

        // ---- MFMA: 4 C-tiles per wave, K=128 ----
        v4f acc[4];
        #pragma unroll
        for (int cls = 0; cls < 4; ++cls) acc[cls] = bias[cls];
        #pragma unroll
        for (int ks = 0; ks < 4; ++ks) {
            #pragma unroll
            for (int cls = 0; cls < 4; ++cls)
                acc[cls] = __builtin_amdgcn_mfma_f32_16x16x32_bf16(
                    afr[cls][ks], bf[ks], acc[cls], 0, 0, 0);
        }

        // ---- pack f16 -> tbuf[par][t16=ml][gate] ----
        #pragma unroll
        for (int cls = 0; cls < 4; ++cls) {
            uint2 pk;
            pk.x = pkh2(acc[cls][0], acc[cls][1]);
            pk.y = pkh2(acc[cls][2], acc[cls][3]);
            *(uint2*)&tbuf[par][ml][cls * 64 + wv * 16 + q * 4] = pk;
        }
        // LDS-only fence + raw barrier: vmcnt NOT drained (prefetch in flight)
        asm volatile("s_waitcnt lgkmcnt(0)" ::: "memory");
        __builtin_amdgcn_s_barrier();
        asm volatile("" ::: "memory");

        // ---- coalesced store: block writes 8 KB contiguous ----
        {
            const int tr = tid >> 4, seg = tid & 15;
            uint4 r0 = *(const uint4*)&tbuf[par][tr][seg * 16];
            uint4 r1 = *(const uint4*)&tbuf[par][tr][seg * 16 + 8];
            unsigned short* orow = xp
                + ((size_t)b * T_ + half * 128 + tl * 16 + tr) * G_ + seg * 16;
            *(uint4*)orow       = r0;
            *(uint4*)(orow + 8) = r1;
        }
        // WAR on tbuf[par] (rewritten at tl+2) is safe: every wave's tl-reads
        // drain at its own lgkmcnt(0) before bar_{tl+1}; no wave reaches
        // tl+2's writes until all passed bar_{tl+1}.
    }
}

// ---------------------------------------------------------------------------
// Phase 2 (reverted to R1's measured-good kernel, 169 us): fully
// wave-synchronous recurrence. One 64-lane wave per batch element
// (1024 blocks x 64 thr). Lane l owns gate rows {l, 64+l, 128+l, 192+l};
// cell update is lane-local. W_hh in 128 VGPRs as packed f16. h exchanged
// via a 128 B LDS buffer with a bare s_waitcnt lgkmcnt(0) -- no barrier,
// no vmcnt drain, so the per-step xp prefetch stays in flight.
// (R2/R4 lesson: any per-step inter-wave barrier costs more than halving
// per-lane dot2 work saves -- do NOT split gates across waves.)
// ---------------------------------------------------------------------------
__global__ __launch_bounds__(64, 1)
void rec_wave_kernel(const unsigned short* __restrict__ xp,  // [B][T][256] f16
                     const float* __restrict__ W_hh,   // [256,64]
                     const float* __restrict__ W1,     // [32,64]
                     const float* __restrict__ b1,     // [32]
                     const float* __restrict__ W2,     // [1,32]
                     const float* __restrict__ b2,     // [1]
                     float* __restrict__ out)          // [B]
{
    const int b    = blockIdx.x;
    const int lane = threadIdx.x;    // 0..63

    __shared__ __align__(16) unsigned hb[2][32];   // h as 64 f16, dbuf
    __shared__ float hf[H_];
    __shared__ float ys[32];

    // ---- W_hh rows {lane, 64+lane, 128+lane, 192+lane} -> 32 uint4 ----
    uint4 wp[4][8];
    #pragma unroll
    for (int r = 0; r < 4; ++r) {
        const float* p = W_hh + (size_t)(r * 64 + lane) * H_;
        #pragma unroll
        for (int k8 = 0; k8 < 8; ++k8) {
            float4 v0 = ((const float4*)(p + k8 * 8))[0];
            float4 v1 = ((const float4*)(p + k8 * 8))[1];
            wp[r][k8].x = pkh2(v0.x, v0.y);
            wp[r][k8].y = pkh2(v0.z, v0.w);
            wp[r][k8].z = pkh2(v1.x, v1.y);
            wp[r][k8].w = pkh2(v1.z, v1.w);
        }
    }

    if (lane < 32) { hb[0][lane] = 0u; hb[1][lane] = 0u; }  // h(0) = 0
    float c = 0.0f, hval = 0.0f;

    const unsigned short* __restrict__ xptr = xp + (size_t)b * T_ * G_ + lane;
    // preload t=0 gates (coalesced 128B per 64-lane load, x4)
    unsigned short xv0 = xptr[0],   xv1 = xptr[64];
    unsigned short xv2 = xptr[128], xv3 = xptr[192];
    __syncthreads();   // once: hb zeros visible

    for (int t = 0; t < T_; ++t) {
        // ---- prefetch next step's xp (consumed after this step's matvec) ----
        const unsigned short* xnp =
            xptr + (size_t)((t + 1 < T_) ? t + 1 : T_ - 1) * G_;
        unsigned short xn0 = xnp[0],   xn1 = xnp[64];
        unsigned short xn2 = xnp[128], xn3 = xnp[192];

        // ---- matvec: 4 gate rows x K=64, f16 dot2, f32 accumulate ----
        const int par = t & 1;
        const uint4* hb4 = (const uint4*)hb[par];
        float a0[4] = {0.f, 0.f, 0.f, 0.f};
        float a1[4] = {0.f, 0.f, 0.f, 0.f};
        #pragma unroll
        for (int k8 = 0; k8 < 8; ++k8) {
            uint4 hv = hb4[k8];              // broadcast b128, conflict-free
            #pragma unroll
            for (int r = 0; r < 4; ++r) {
                a0[r] = fdot2_(wp[r][k8].x, hv.x, a0[r]);
                a1[r] = fdot2_(wp[r][k8].y, hv.y, a1[r]);
                a0[r] = fdot2_(wp[r][k8].z, hv.z, a0[r]);
                a1[r] = fdot2_(wp[r][k8].w, hv.w, a1[r]);
            }
        }
        float pre0 = (float)__builtin_bit_cast(_Float16, xv0) + (a0[0] + a1[0]);
        float pre1 = (float)__builtin_bit_cast(_Float16, xv1) + (a0[1] + a1[1]);
        float pre2 = (float)__builtin_bit_cast(_Float16, xv2) + (a0[2] + a1[2]);
        float pre3 = (float)__builtin_bit_cast(_Float16, xv3) + (a0[3] + a1[3]);

        // ---- lane-local gate activations + cell update ----
        float gi = sigmoidf_(pre0);
        float gf = sigmoidf_(pre1);
        float gg = tanhf_(pre2);
        float go = sigmoidf_(pre3);
        c    = fmaf(gf, c, gi * gg);
        hval = go * tanhf_(c);

        // ---- publish h(t+1): 2B/lane, then LDS-only fence (no barrier) ----
        ((_Float16*)hb[par ^ 1])[lane] = (_Float16)hval;
        asm volatile("s_waitcnt lgkmcnt(0)" ::: "memory");

        xv0 = xn0; xv1 = xn1; xv2 = xn2; xv3 = xn3;
    }

    // ---- head (once) ----
    hf[lane] = hval;
    __syncthreads();
    if (lane < 32) {
        float acc = b1[lane];
        const float4* w1r = (const float4*)(W1 + (size_t)lane * H_);
        #pragma unroll
        for (int k4 = 0; k4 < 16; ++k4) {
            float4 h4 = *(const float4*)&hf[k4 * 4];
            float4 w4 = w1r[k4];
            acc = fmaf(w4.x, h4.x, acc); acc = fmaf(w4.y, h4.y, acc);
            acc = fmaf(w4.z, h4.z, acc); acc = fmaf(w4.w, h4.w, acc);
        }
        ys[lane] = fmaxf(acc, 0.0f);
    }
    __syncthreads();
    if (lane == 0) {
        float acc = b2[0];
        #pragma unroll
        for (int j = 0; j < 32; ++j) acc = fmaf(W2[j], ys[j], acc);
        out[b] = sigmoidf_(acc);
    }
}

// ---------------------------------------------------------------------------
// Fallback: round-1 fused fp32 kernel (used only if workspace too small).
// ---------------------------------------------------------------------------
__global__ __launch_bounds__(256, 2)
void lstm_fused_kernel(const float* __restrict__ x,
                       const float* __restrict__ W_ih,
                       const float* __restrict__ W_hh,
                       const float* __restrict__ b_ih,
                       const float* __restrict__ b_hh,
                       const float* __restrict__ W1,
                       const float* __restrict__ b1,
                       const float* __restrict__ W2,
                       const float* __restrict__ b2,
                       float* __restrict__ out)
{
    const int b = blockIdx.x;
    const int g = threadIdx.x;

    __shared__ __align__(16) float xs[D_];
    __shared__ __align__(16) float hs[H_];
    __shared__ __align__(16) float gts[G_];
    __shared__ __align__(16) float yss[32];

    float wih[D_];
    float whhr[H_];
    {
        const float4* wr = (const float4*)(W_ih + (size_t)g * D_);
        #pragma unroll
        for (int k = 0; k < D_ / 4; ++k) {
            float4 v = wr[k];
            wih[4*k+0] = v.x; wih[4*k+1] = v.y;
            wih[4*k+2] = v.z; wih[4*k+3] = v.w;
        }
    }
    {
        const float4* wr = (const float4*)(W_hh + (size_t)g * H_);
        #pragma unroll
        for (int k = 0; k < H_ / 4; ++k) {
            float4 v = wr[k];
            whhr[4*k+0] = v.x; whhr[4*k+1] = v.y;
            whhr[4*k+2] = v.z; whhr[4*k+3] = v.w;
        }
    }
    const float bg  = b_ih[g] + b_hh[g];
    const int   cls = g >> 6;

    float c = 0.0f;
    if (g < H_) hs[g] = 0.0f;

    const float* __restrict__ xrow = x + (size_t)b * T_ * D_;

    for (int t = 0; t < T_; ++t) {
        if (g < D_) xs[g] = xrow[(size_t)t * D_ + g];
        __syncthreads();

        float a0 = bg, a1 = 0.f, a2 = 0.f, a3 = 0.f;
        const float4* xs4 = (const float4*)xs;
        #pragma unroll
        for (int k = 0; k < D_ / 4; ++k) {
            float4 v = xs4[k];
            a0 = fmaf(wih[4*k+0], v.x, a0);
            a1 = fmaf(wih[4*k+1], v.y, a1);
            a2 = fmaf(wih[4*k+2], v.z, a2);
            a3 = fmaf(wih[4*k+3], v.w, a3);
        }
        const float4* hs4 = (const float4*)hs;
        #pragma unroll
        for (int k = 0; k < H_ / 4; ++k) {
            float4 v = hs4[k];
            a0 = fmaf(whhr[4*k+0], v.x, a0);
            a1 = fmaf(whhr[4*k+1], v.y, a1);
            a2 = fmaf(whhr[4*k+2], v.z, a2);
            a3 = fmaf(whhr[4*k+3], v.w, a3);
        }
        float acc = (a0 + a1) + (a2 + a3);
        gts[g] = (cls == 2) ? tanhf_(acc) : sigmoidf_(acc);
        __syncthreads();

        if (g < H_) {
            float gi = gts[g];
            float gf = gts[H_ + g];
            float gg = gts[2 * H_ + g];
            float go = gts[3 * H_ + g];
            c = fmaf(gf, c, gi * gg);
            hs[g] = go * tanhf_(c);
        }
    }
    __syncthreads();

    if (g < 32) {
        float acc = b1[g];
        const float* w1r = W1 + g * H_;
        #pragma unroll
        for (int k = 0; k < H_; ++k) acc = fmaf(w1r[k], hs[k], acc);
        yss[g] = fmaxf(acc, 0.0f);
    }
    __syncthreads();
    if (g == 0) {
        float acc = b2[0];
        #pragma unroll
        for (int k = 0; k < 32; ++k) acc = fmaf(W2[k], yss[k], acc);
        out[b] = sigmoidf_(acc);
    }
}

extern "C" void kernel_launch(void* const* d_in, const int* in_sizes, int n_in,
                              void* d_out, int out_size, void* d_ws, size_t ws_size,
                              hipStream_t stream) {
    const float* x    = (const float*)d_in[0];
    const float* W_ih = (const float*)d_in[1];
    const float* W_hh = (const float*)d_in[2];
    const float* b_ih = (const float*)d_in[3];
    const float* b_hh = (const float*)d_in[4];
    const float* W1   = (const float*)d_in[5];
    const float* b1   = (const float*)d_in[6];
    const float* W2   = (const float*)d_in[7];
    const float* b2   = (const float*)d_in[8];
    float* out = (float*)d_out;

    const size_t xp_bytes = (size_t)M_ * G_ * sizeof(unsigned short);  // 134 MB

    if (ws_size >= xp_bytes) {
        unsigned short* xp = (unsigned short*)d_ws;
        xproj2_kernel<<<dim3(2, 1024), dim3(256), 0, stream>>>(
            x, W_ih, b_ih, b_hh, xp);
        rec_wave_kernel<<<dim3(B_), dim3(64), 0, stream>>>(
            xp, W_hh, W1, b1, W2, b2, out);
    } else {
        lstm_fused_kernel<<<dim3(B_), dim3(256), 0, stream>>>(
            x, W_ih, W_hh, b_ih, b_hh, W1, b1, W2, b2, out);
    }
}